// Round 6
// baseline (371.019 us; speedup 1.0000x reference)
//
#include <hip/hip_runtime.h>
#include <hip/hip_bf16.h>
#include <stdint.h>

// B=4, N=8192, E=1024, D=64 ; ROWS = 32768
// out = Q @ F,  F = sqrt(3/64) * (K^T V) @ wo^T,  Q/K/V = x @ w{q,k,v}^T
// Precision: weights exact in bf16; activations split hi/lo bf16 -> fp32 MFMA acc.
//
// R6: compiler-proof pipelining.
//  - K1: m97 template. x staged fp32 via global_load_lds (dbuf, 1 barrier/step,
//    source-permuted XOR swizzle so ds_read_b128 is conflict-free). B-frags from
//    L2-hot Wb issued before the stage (counted vmcnt keeps stage in flight).
//  - F-fold kills the ctx stage; K3 is a single-K-step GEMM -> no serial chain,
//    latency hidden by TLP alone (2048 blocks, no LDS, no barriers).

typedef __bf16 bf16x8 __attribute__((ext_vector_type(8)));
typedef __bf16 bf16x4 __attribute__((ext_vector_type(4)));
typedef float  f32x4  __attribute__((ext_vector_type(4)));

#define MFMA_BF16(A, Bb, C) __builtin_amdgcn_mfma_f32_16x16x32_bf16(A, Bb, C, 0, 0, 0)

__device__ __forceinline__ void gload_lds16(const void* g, void* l) {
    __builtin_amdgcn_global_load_lds(
        (const __attribute__((address_space(1))) unsigned int*)g,
        (__attribute__((address_space(3))) unsigned int*)l, 16, 0, 0);
}

__device__ __forceinline__ void split8(const float* f, bf16x8& h, bf16x8& l) {
#pragma unroll
    for (int j = 0; j < 8; ++j) {
        const unsigned int u = __float_as_uint(f[j]);
        h[j] = __builtin_bit_cast(__bf16, (unsigned short)(u >> 16));
        l[j] = (__bf16)(f[j] - __uint_as_float(u & 0xffff0000u));
    }
}

// ---------------------------------------------------------------------------
// P0: fp32->bf16 cast of [wq|wk|wv|wo] -> Wb[192][1024] ++ Wob[1024][64].
// ---------------------------------------------------------------------------
__global__ __launch_bounds__(128) void prep_kernel(
    const float* __restrict__ wq, const float* __restrict__ wk,
    const float* __restrict__ wv, const float* __restrict__ wo,
    __bf16* __restrict__ Wb)
{
    const int gid = blockIdx.x * 128 + threadIdx.x;      // 0..32767
    const int e0  = gid * 8;
    const float* src = (e0 < 65536)  ? wq + e0
                     : (e0 < 131072) ? wk + (e0 - 65536)
                     : (e0 < 196608) ? wv + (e0 - 131072)
                                     : wo + (e0 - 196608);
    float w[8];
    *(float4*)&w[0] = *(const float4*)(src);
    *(float4*)&w[4] = *(const float4*)(src + 4);
    bf16x8 wb;
#pragma unroll
    for (int j = 0; j < 8; ++j) wb[j] = (__bf16)w[j];
    *(bf16x8*)&Wb[e0] = wb;
}

// ---------------------------------------------------------------------------
// K1: QKV GEMM (m97 template).  C[32768 x 192] = split(x) @ Wb^T.
// 512 blocks x 512 thr (8 waves = 4 rowgrp x 2 colgrp); tile 64r x 192c; BK=64.
// x-tile fp32 in LDS via global_load_lds, dbuf, 1 syncthreads/step.
// LDS content XOR-swizzled via per-lane SOURCE permutation (dest stays linear):
//   LDS 16B-chunk (r, c) holds x chunk (r, c ^ (r&7))  -> ds_read 2-way free.
// ---------------------------------------------------------------------------
__global__ __launch_bounds__(512, 4) void qkv_kernel(
    const float* __restrict__ x, const __bf16* __restrict__ Wb,
    float* __restrict__ Qf, float* __restrict__ Kf, float* __restrict__ Vf)
{
    __shared__ float xt[2][64 * 64];                 // 2 x 16 KB

    const int tid  = threadIdx.x;
    const int lane = tid & 63;
    const int wid  = tid >> 6;          // 0..7
    const int lr   = lane & 15;
    const int kg   = lane >> 4;
    const int wr   = wid >> 1;          // 0..3 : 16-row group
    const int wc   = wid & 1;           // 0..1 : 96-col group
    const int row0 = blockIdx.x * 64;

    // staging: 16 x 1KB calls/step, 2 per wave. slot s=(q*64+lane): r=s>>4, c=s&15
    const int q0 = wid * 2;
    const int s0 = q0 * 64 + lane;
    const int s1 = s0 + 64;
    const int r0 = s0 >> 4, c0 = s0 & 15;
    const int r1 = s1 >> 4, c1 = s1 & 15;
    const float* src0 = x + (size_t)(row0 + r0) * 1024 + (c0 ^ (r0 & 7)) * 4;
    const float* src1 = x + (size_t)(row0 + r1) * 1024 + (c1 ^ (r1 & 7)) * 4;

#define STAGE(stp, buf) {                                                      \
        gload_lds16(src0 + (stp) * 64, (char*)&xt[buf][0] + (q0 + 0) * 1024);  \
        gload_lds16(src1 + (stp) * 64, (char*)&xt[buf][0] + (q0 + 1) * 1024); }

    f32x4 acc[6];
#pragma unroll
    for (int i = 0; i < 6; ++i) acc[i] = (f32x4){0.f, 0.f, 0.f, 0.f};

    STAGE(0, 0);

    const int ar  = wr * 16 + lr;                    // A row in tile
    const int am  = ar & 7;                          // swizzle key

    for (int step = 0; step < 16; ++step) {
        const int cur = step & 1;
        __syncthreads();                             // drains stage(cur)

        // B-frags FIRST (oldest in vmem queue -> waiting them leaves stage alive)
        bf16x8 Bw[2][6];
#pragma unroll
        for (int ks = 0; ks < 2; ++ks)
#pragma unroll
            for (int n = 0; n < 6; ++n)
                Bw[ks][n] = *(const bf16x8*)&Wb[(size_t)(wc * 96 + n * 16 + lr) * 1024
                                                + step * 64 + ks * 32 + kg * 8];
        if (step + 1 < 16) STAGE(step + 1, cur ^ 1);

        // A-frags: ds_read fp32 (swizzled chunks), split hi/lo once
        bf16x8 Ah[2], Al[2];
#pragma unroll
        for (int ks = 0; ks < 2; ++ks) {
            const int g0 = ks * 8 + kg * 2;
            float f[8];
            *(f32x4*)&f[0] = *(const f32x4*)&xt[cur][ar * 64 + ((g0    ) ^ am) * 4];
            *(f32x4*)&f[4] = *(const f32x4*)&xt[cur][ar * 64 + ((g0 + 1) ^ am) * 4];
            split8(f, Ah[ks], Al[ks]);
        }
#pragma unroll
        for (int ks = 0; ks < 2; ++ks)
#pragma unroll
            for (int n = 0; n < 6; ++n) {
                acc[n] = MFMA_BF16(Ah[ks], Bw[ks][n], acc[n]);
                acc[n] = MFMA_BF16(Al[ks], Bw[ks][n], acc[n]);
            }
    }
#undef STAGE

    // epilogue: C/D layout col=lane&15, row=(lane>>4)*4+reg
#pragma unroll
    for (int n = 0; n < 6; ++n) {
        const int col  = wc * 96 + n * 16 + lr;
        const int rowb = row0 + wr * 16 + kg * 4;
        float* dst = (col < 64) ? Qf : (col < 128) ? Kf : Vf;
        const int cc = col & 63;
#pragma unroll
        for (int r = 0; r < 4; ++r)
            dst[(size_t)(rowb + r) * 64 + cc] = acc[n][r];
    }
}

// ---------------------------------------------------------------------------
// K2: partial energy.  part[blk][d][e] = sum over 64 rows of K[n,d]*V[n,e].
// ---------------------------------------------------------------------------
__global__ __launch_bounds__(256) void energy_partial_kernel(
    const float* __restrict__ Kf, const float* __restrict__ Vf,
    float* __restrict__ part)
{
    __shared__ float lK[64 * 64];
    __shared__ float lV[64 * 64];
    const int tid  = threadIdx.x;
    const int row0 = blockIdx.x * 64;

#pragma unroll
    for (int i = 0; i < 4; ++i) {
        const int idx = tid + i * 256;
        const int r   = idx >> 4;
        const int c4  = (idx & 15) << 2;
        *(float4*)&lK[r * 64 + c4] = *(const float4*)&Kf[(size_t)(row0 + r) * 64 + c4];
        *(float4*)&lV[r * 64 + c4] = *(const float4*)&Vf[(size_t)(row0 + r) * 64 + c4];
    }
    __syncthreads();

    const int d  = tid & 63;
    const int eb = (tid >> 6) * 16;
    float acc[16];
#pragma unroll
    for (int j = 0; j < 16; ++j) acc[j] = 0.f;

    for (int n = 0; n < 64; ++n) {
        const float kd = lK[n * 64 + d];
        const float4 v0 = *(const float4*)&lV[n * 64 + eb];
        const float4 v1 = *(const float4*)&lV[n * 64 + eb + 4];
        const float4 v2 = *(const float4*)&lV[n * 64 + eb + 8];
        const float4 v3 = *(const float4*)&lV[n * 64 + eb + 12];
        acc[0]  += kd * v0.x; acc[1]  += kd * v0.y; acc[2]  += kd * v0.z; acc[3]  += kd * v0.w;
        acc[4]  += kd * v1.x; acc[5]  += kd * v1.y; acc[6]  += kd * v1.z; acc[7]  += kd * v1.w;
        acc[8]  += kd * v2.x; acc[9]  += kd * v2.y; acc[10] += kd * v2.z; acc[11] += kd * v2.w;
        acc[12] += kd * v3.x; acc[13] += kd * v3.y; acc[14] += kd * v3.z; acc[15] += kd * v3.w;
    }
    float* p = part + (size_t)blockIdx.x * 4096 + d * 64 + eb;
#pragma unroll
    for (int i = 0; i < 4; ++i)
        *(float4*)&p[i * 4] = make_float4(acc[i*4], acc[i*4+1], acc[i*4+2], acc[i*4+3]);
}

// K2b: reduce 128 partials/batch, fold sqrt(3/64); E row-major [d][e] hi/lo bf16.
__global__ __launch_bounds__(256) void energy_reduce_kernel(
    const float* __restrict__ part, __bf16* __restrict__ Eh, __bf16* __restrict__ El)
{
    const int b    = blockIdx.x >> 4;
    const int elem = ((blockIdx.x & 15) << 8) + threadIdx.x;   // d*64+e
    float s = 0.f;
#pragma unroll 8
    for (int c = 0; c < 128; ++c)
        s += part[(size_t)(b * 128 + c) * 4096 + elem];
    s *= 0.2165063509461097f;                                  // sqrt(3/64)
    const __bf16 h = (__bf16)s;
    const __bf16 l = (__bf16)(s - (float)h);
    Eh[b * 4096 + elem] = h;
    El[b * 4096 + elem] = l;
}

// ---------------------------------------------------------------------------
// K2c: F[d1][e'] = sum_e E[d1][e]*wo[e'][e]  (scale already in E).
// Output transposed: Fth/Ftl[b][e'][d1] bf16 hi/lo (K3 B-frag layout).
// 16 blocks x 256 thr; wave = 16 d-rows x 256 cols.
// ---------------------------------------------------------------------------
__global__ __launch_bounds__(256) void f_kernel(
    const __bf16* __restrict__ Eh, const __bf16* __restrict__ El,
    const __bf16* __restrict__ Wob,
    __bf16* __restrict__ Fth, __bf16* __restrict__ Ftl)
{
    const int tid  = threadIdx.x;
    const int lane = tid & 63;
    const int wid  = tid >> 6;          // d-row group
    const int lr   = lane & 15;
    const int kg   = lane >> 4;
    const int b    = blockIdx.x >> 2;
    const int cg   = blockIdx.x & 3;    // 256-col group

    // A-frags: E rows wid*16+lr (bf16 already)
    bf16x8 Ah[2], Al[2];
#pragma unroll
    for (int ks = 0; ks < 2; ++ks) {
        const size_t o = (size_t)b * 4096 + (wid * 16 + lr) * 64 + ks * 32 + kg * 8;
        Ah[ks] = *(const bf16x8*)&Eh[o];
        Al[ks] = *(const bf16x8*)&El[o];
    }

#pragma unroll
    for (int grp = 0; grp < 4; ++grp) {
        f32x4 acc[4];
#pragma unroll
        for (int i = 0; i < 4; ++i) acc[i] = (f32x4){0.f, 0.f, 0.f, 0.f};
        bf16x8 Bw[4][2];
#pragma unroll
        for (int n = 0; n < 4; ++n)
#pragma unroll
            for (int ks = 0; ks < 2; ++ks) {
                const int col = cg * 256 + grp * 64 + n * 16 + lr;
                Bw[n][ks] = *(const bf16x8*)&Wob[(size_t)col * 64 + ks * 32 + kg * 8];
            }
#pragma unroll
        for (int ks = 0; ks < 2; ++ks)
#pragma unroll
            for (int n = 0; n < 4; ++n) {
                acc[n] = MFMA_BF16(Ah[ks], Bw[n][ks], acc[n]);
                acc[n] = MFMA_BF16(Al[ks], Bw[n][ks], acc[n]);
            }
#pragma unroll
        for (int n = 0; n < 4; ++n) {
            const int col = cg * 256 + grp * 64 + n * 16 + lr;
            bf16x4 hv, lv;
#pragma unroll
            for (int r = 0; r < 4; ++r) {
                const float v = acc[n][r];
                hv[r] = (__bf16)v;
                lv[r] = (__bf16)(v - (float)hv[r]);
            }
            const size_t o = (size_t)b * 65536 + (size_t)col * 64 + wid * 16 + kg * 4;
            *(bf16x4*)&Fth[o] = hv;
            *(bf16x4*)&Ftl[o] = lv;
        }
    }
}

// ---------------------------------------------------------------------------
// K3: out = Q @ F.  Single K-step (K=64) -> no serial chain; pure TLP.
// 2048 blocks x 256 thr (4 waves); wave = 16 rows x 256 cols; no LDS/barriers.
// ---------------------------------------------------------------------------
__global__ __launch_bounds__(256, 4) void out_kernel(
    const float* __restrict__ Qf,
    const __bf16* __restrict__ Fth, const __bf16* __restrict__ Ftl,
    float* __restrict__ out)
{
    const int tid    = threadIdx.x;
    const int lane   = tid & 63;
    const int wid    = tid >> 6;
    const int lr     = lane & 15;
    const int kg     = lane >> 4;
    const int rowblk = blockIdx.x >> 2;
    const int cg     = blockIdx.x & 3;
    const int row0   = rowblk * 64 + wid * 16;
    const int b      = rowblk >> 7;

    // A-frags: Q rows row0+lr, split hi/lo
    bf16x8 Qh[2], Ql[2];
#pragma unroll
    for (int ks = 0; ks < 2; ++ks) {
        float f[8];
        const float* src = &Qf[(size_t)(row0 + lr) * 64 + ks * 32 + kg * 8];
        *(float4*)&f[0] = *(const float4*)(src);
        *(float4*)&f[4] = *(const float4*)(src + 4);
        split8(f, Qh[ks], Ql[ks]);
    }

    const size_t fb = (size_t)b * 65536;
#pragma unroll
    for (int grp = 0; grp < 4; ++grp) {
        bf16x8 Bh[4][2], Bl[4][2];
#pragma unroll
        for (int n = 0; n < 4; ++n)
#pragma unroll
            for (int ks = 0; ks < 2; ++ks) {
                const size_t o = fb + (size_t)(cg * 256 + grp * 64 + n * 16 + lr) * 64
                               + ks * 32 + kg * 8;
                Bh[n][ks] = *(const bf16x8*)&Fth[o];
                Bl[n][ks] = *(const bf16x8*)&Ftl[o];
            }
        f32x4 acc[4];
#pragma unroll
        for (int i = 0; i < 4; ++i) acc[i] = (f32x4){0.f, 0.f, 0.f, 0.f};
#pragma unroll
        for (int ks = 0; ks < 2; ++ks)
#pragma unroll
            for (int n = 0; n < 4; ++n) {
                acc[n] = MFMA_BF16(Qh[ks], Bh[n][ks], acc[n]);
                acc[n] = MFMA_BF16(Qh[ks], Bl[n][ks], acc[n]);
                acc[n] = MFMA_BF16(Ql[ks], Bh[n][ks], acc[n]);
            }
#pragma unroll
        for (int n = 0; n < 4; ++n) {
            const int col = cg * 256 + grp * 64 + n * 16 + lr;
#pragma unroll
            for (int r = 0; r < 4; ++r)
                __builtin_nontemporal_store(acc[n][r],
                    &out[(size_t)(row0 + kg * 4 + r) * 1024 + col]);
        }
    }
}

extern "C" void kernel_launch(void* const* d_in, const int* in_sizes, int n_in,
                              void* d_out, int out_size, void* d_ws, size_t ws_size,
                              hipStream_t stream)
{
    const float* x  = (const float*)d_in[0];
    const float* wq = (const float*)d_in[1];
    const float* wk = (const float*)d_in[2];
    const float* wv = (const float*)d_in[3];
    const float* wo = (const float*)d_in[4];
    float* out = (float*)d_out;

    char* ws = (char*)d_ws;
    float*  Qf   = (float*)(ws);                          //  8 MB
    float*  Kf   = (float*)(ws + 8388608);                //  8 MB
    float*  Vf   = (float*)(ws + 16777216);               //  8 MB
    float*  part = (float*)(ws + 25165824);               //  8 MB (512*4096*4)
    __bf16* Wb   = (__bf16*)(ws + 33554432);              //  512 KB
    __bf16* Wob  = Wb + 196608;
    __bf16* Eh   = (__bf16*)(ws + 34078720);              //  32 KB
    __bf16* El   = (__bf16*)(ws + 34111488);              //  32 KB
    __bf16* Fth  = (__bf16*)(ws + 34144256);              //  512 KB
    __bf16* Ftl  = (__bf16*)(ws + 34668544);              //  512 KB

    prep_kernel<<<256, 128, 0, stream>>>(wq, wk, wv, wo, Wb);
    qkv_kernel<<<512, 512, 0, stream>>>(x, Wb, Qf, Kf, Vf);
    energy_partial_kernel<<<512, 256, 0, stream>>>(Kf, Vf, part);
    energy_reduce_kernel<<<64, 256, 0, stream>>>(part, Eh, El);
    f_kernel<<<16, 256, 0, stream>>>(Eh, El, Wob, Fth, Ftl);
    out_kernel<<<2048, 256, 0, stream>>>(Qf, Fth, Ftl, out);
}